// Round 1
// 211.613 us; speedup vs baseline: 1.0089x; 1.0089x over previous
//
#include <hip/hip_runtime.h>

// Dice coefficient: argmax over C=4 classes per pixel + histogram counts.
// Shapes fixed by the problem: B=32, C=4, H=W=512.
constexpr int kHW      = 512 * 512;          // 262144 pixels per plane
constexpr int kC       = 4;
constexpr int kB       = 32;
constexpr int kGroups  = kB * kHW / 4;       // 2097152 float4-groups
constexpr int kBlocks  = 2048;               // 8 blocks/CU heuristic (G11)
constexpr int kThreads = 256;
constexpr int kStride  = kBlocks * kThreads; // 524288
constexpr int kIters   = kGroups / kStride;  // 4 (exact)
static_assert(kGroups % kStride == 0, "grid must tile the group count exactly");

// ws layout: per-block partials, 3 x u64 per block (packed 4x16-bit fields).
// Every slot is written unconditionally -> NO zero-init / memset dispatch needed.
// part[b*3 + 0] = pred_cnt, +1 = true_cnt, +2 = tp.
// Field bound: 4 iters * 4 px * 256 thr = 4096 per block per class < 2^16. OK.

__global__ __launch_bounds__(kThreads)
void dice_count_kernel(const int* __restrict__ tm, const float* __restrict__ outp,
                       unsigned long long* __restrict__ part) {
    unsigned long long predp = 0, truep = 0, tpp = 0;
    const int tid0 = blockIdx.x * kThreads + threadIdx.x;

    // Fully unrolled: 4 iters x (4 float4 + 1 int4) = 20 independent loads in
    // flight per thread -> deep MLP for the BW-bound stream.
    #pragma unroll
    for (int it = 0; it < kIters; ++it) {
        const int g   = tid0 + it * kStride;
        const int b   = g >> 16;             // 65536 float4-groups per plane
        const int rem = (g & 0xFFFF) << 2;   // pixel offset within the plane
        const float* base = outp + ((size_t)b * kC) * kHW + rem;
        const float4 v0 = *(const float4*)(base);
        const float4 v1 = *(const float4*)(base + kHW);
        const float4 v2 = *(const float4*)(base + 2 * kHW);
        const float4 v3 = *(const float4*)(base + 3 * kHW);
        const int4   t  = *(const int4*)(tm + (size_t)g * 4);

        // First-max-wins argmax (strict >) matches jnp.argmax semantics.
        #define DO_PIXEL(f, tf)                                        \
        {                                                              \
            int   pred = 0;                                            \
            float best = v0.f;                                         \
            if (v1.f > best) { best = v1.f; pred = 1; }                \
            if (v2.f > best) { best = v2.f; pred = 2; }                \
            if (v3.f > best) { best = v3.f; pred = 3; }                \
            predp += 1ull << (pred << 4);                              \
            truep += 1ull << (t.tf << 4);                              \
            if (pred == t.tf) tpp += 1ull << (pred << 4);              \
        }
        DO_PIXEL(x, x) DO_PIXEL(y, y) DO_PIXEL(z, z) DO_PIXEL(w, w)
        #undef DO_PIXEL
    }

    // Wave-64 butterfly reduction (fields <= 1024/wave, fits 16 bits).
    for (int off = 32; off > 0; off >>= 1) {
        predp += __shfl_down(predp, off);
        truep += __shfl_down(truep, off);
        tpp   += __shfl_down(tpp, off);
    }

    __shared__ unsigned long long s[3][4];
    const int lane = threadIdx.x & 63;
    const int wave = threadIdx.x >> 6;
    if (lane == 0) { s[0][wave] = predp; s[1][wave] = truep; s[2][wave] = tpp; }
    __syncthreads();

    if (threadIdx.x == 0) {
        // Block totals <= 4096 per field: still fits the 16-bit packing.
        part[(size_t)blockIdx.x * 3 + 0] = s[0][0] + s[0][1] + s[0][2] + s[0][3];
        part[(size_t)blockIdx.x * 3 + 1] = s[1][0] + s[1][1] + s[1][2] + s[1][3];
        part[(size_t)blockIdx.x * 3 + 2] = s[2][0] + s[2][1] + s[2][2] + s[2][3];
    }
}

__global__ __launch_bounds__(256)
void dice_final_kernel(const unsigned long long* __restrict__ part,
                       float* __restrict__ out) {
    // Unpack per-block 16-bit fields to 32-bit BEFORE summing across blocks
    // (grid totals reach 8.4M >> 2^16).
    unsigned acc[12];
    #pragma unroll
    for (int i = 0; i < 12; ++i) acc[i] = 0;

    for (int k = threadIdx.x; k < kBlocks; k += 256) {
        const unsigned long long P = part[(size_t)k * 3 + 0];
        const unsigned long long T = part[(size_t)k * 3 + 1];
        const unsigned long long Q = part[(size_t)k * 3 + 2];
        #pragma unroll
        for (int c = 0; c < 4; ++c) {
            acc[c]     += (unsigned)((P >> (c * 16)) & 0xFFFF);
            acc[4 + c] += (unsigned)((T >> (c * 16)) & 0xFFFF);
            acc[8 + c] += (unsigned)((Q >> (c * 16)) & 0xFFFF);
        }
    }

    #pragma unroll
    for (int i = 0; i < 12; ++i)
        for (int off = 32; off > 0; off >>= 1)
            acc[i] += __shfl_down(acc[i], off);

    __shared__ unsigned s[4][12];
    const int lane = threadIdx.x & 63;
    const int wave = threadIdx.x >> 6;
    if (lane == 0) {
        #pragma unroll
        for (int i = 0; i < 12; ++i) s[wave][i] = acc[i];
    }
    __syncthreads();

    if (threadIdx.x == 0) {
        float tot[12];
        #pragma unroll
        for (int i = 0; i < 12; ++i)
            tot[i] = (float)(s[0][i] + s[1][i] + s[2][i] + s[3][i]);
        #pragma unroll
        for (int c = 1; c < 4; ++c)   // classes 1..3 (skip background)
            out[c - 1] = 2.0f * tot[8 + c] / (tot[c] + tot[4 + c]);
    }
}

extern "C" void kernel_launch(void* const* d_in, const int* in_sizes, int n_in,
                              void* d_out, int out_size, void* d_ws, size_t ws_size,
                              hipStream_t stream) {
    const int*   tm = (const int*)d_in[0];    // true_masks [B,H,W] int32
    const float* op = (const float*)d_in[1];  // out        [B,C,H,W] f32
    unsigned long long* part = (unsigned long long*)d_ws;

    // No memset: every partial slot is written unconditionally by its block.
    dice_count_kernel<<<kBlocks, kThreads, 0, stream>>>(tm, op, part);
    dice_final_kernel<<<1, 256, 0, stream>>>(part, (float*)d_out);
}